// Round 4
// baseline (1146.981 us; speedup 1.0000x reference)
//
#include <hip/hip_runtime.h>
#include <hip/hip_bf16.h>

#define HW 16384
#define NB 8
#define CIN 64

typedef short short8 __attribute__((ext_vector_type(8)));
typedef float f32x4 __attribute__((ext_vector_type(4)));

// ---------------- ws layout (BYTE offsets) ----------------
// xt      : [8][HW][64] bf16      0           16,777,216
// wrh     : [2][9][64co][64ci]    16777216    147,456
// woh     : [32co][9tap][64ci]    16924672    36,864 (slot 73,728)
// off_raw : [16][9][HW] f32       17000448    9,437,184
// bn_stat : [18][2] f32           26437632    144
// gnp     : [16][512][16][2] f32  26439168    1,048,576   (aliased: bnp2 [18][4096][2] early)
// gn_stat : [256][2] f32          27487744    2,048
#define XT_OFF   0
#define WRH_OFF  16777216
#define WOH_OFF  16924672
#define RAW_OFF  17000448
#define BNS_OFF  26437632
#define GNP_OFF  26439168
#define GNS_OFF  27487744

__device__ inline unsigned short f2b(float v) {
    __hip_bfloat16 h = __float2bfloat16(v);
    unsigned short u; __builtin_memcpy(&u, &h, 2);
    return u;
}
__device__ inline float bperm_f(int srclane, float v) {
    int r = __builtin_amdgcn_ds_bpermute(srclane << 2, __builtin_bit_cast(int, v));
    return __builtin_bit_cast(float, r);
}
__device__ inline int bperm_i(int srclane, int v) {
    return __builtin_amdgcn_ds_bpermute(srclane << 2, v);
}

// x [b][ci][px] f32  ->  xt [b][px][ci] bf16
__global__ __launch_bounds__(256) void cvt_x(const float* __restrict__ x,
                                             unsigned short* __restrict__ xt) {
    int blk = blockIdx.x;              // 512 = 8b * 64 tiles(256px)
    int b = blk >> 6;
    int px0 = (blk & 63) * 256;
    int t = threadIdx.x;
    __shared__ unsigned short lds[256][72];
    const float* xb = x + (size_t)b * CIN * HW + px0;
    for (int ci = 0; ci < 64; ++ci)
        lds[t][ci] = f2b(xb[ci * HW + t]);
    __syncthreads();
    int wv = t >> 6, l = t & 63;
    unsigned short* dst = xt + ((size_t)(b * HW + px0)) * 64;
    for (int it = 0; it < 8; ++it) {
        int row = it * 32 + wv * 8 + (l >> 3);
        short8 v = *(const short8*)&lds[row][(l & 7) * 8];
        *(short8*)&dst[row * 64 + (l & 7) * 8] = v;
    }
}

__global__ __launch_bounds__(256) void repack_w(const float* __restrict__ w0,
                                                const float* __restrict__ w1,
                                                unsigned short* __restrict__ wrh) {
    int i = blockIdx.x * 256 + threadIdx.x;
    if (i >= 2 * 9 * 64 * 64) return;
    int ci = i & 63;
    int co = (i >> 6) & 63;
    int k  = (i >> 12) % 9;
    int br = i / 36864;
    const float* w = br ? w1 : w0;
    wrh[i] = f2b(w[(co * 64 + ci) * 9 + k]);
}

__global__ __launch_bounds__(256) void repack_wo(const float* __restrict__ w0,
                                                 const float* __restrict__ w1,
                                                 unsigned short* __restrict__ woh) {
    int i = blockIdx.x * 256 + threadIdx.x;
    if (i >= 32 * 9 * 64) return;
    int ci = i & 63;
    int tap = (i >> 6) % 9;
    int co = i / 576;
    float v = 0.f;
    if (co < 9)       v = w0[(co * 64 + ci) * 9 + tap];
    else if (co < 18) v = w1[(co * 64 + ci) * 9 + tap];
    woh[i] = f2b(v);
}

// offset 3x3 conv MFMA + fused BN partials. 1024 blocks x 256 (4 waves, 1 tile each)
__global__ __launch_bounds__(256, 6) void off_mfma(const unsigned short* __restrict__ xt,
                                                   const unsigned short* __restrict__ woh,
                                                   float* __restrict__ off_raw,
                                                   float* __restrict__ bnp) {
    int b = blockIdx.x & 7;
    int tgrp = blockIdx.x >> 3;        // 0..127
    int t = threadIdx.x;
    int wid = t >> 6, l = t & 63;
    int tile = tgrp * 4 + wid;         // 0..511
    int l15 = l & 15, kg = l >> 4;
    int px0 = tile * 32;
    int h = px0 >> 7;
    int w0 = px0 & 127;
    const unsigned short* xtb = xt + (size_t)b * HW * 64;

    f32x4 acc[2][2];
#pragma unroll
    for (int m = 0; m < 2; ++m)
#pragma unroll
        for (int nn = 0; nn < 2; ++nn) acc[m][nn] = (f32x4)(0.f);

#pragma unroll
    for (int s = 0; s < 18; ++s) {
        const int tap = s >> 1, ci0 = (s & 1) * 32;
        const int dy = tap / 3 - 1, dx = tap % 3 - 1;
        int y = h + dy;
        bool yok = (unsigned)y < 128u;
        int yc = min(max(y, 0), 127);
        short8 af[2];
#pragma unroll
        for (int m = 0; m < 2; ++m) {
            int xx = w0 + m * 16 + l15 + dx;
            bool ok = yok && ((unsigned)xx < 128u);
            int xc = min(max(xx, 0), 127);
            int o = yc * 128 + xc;
            short8 a = *(const short8*)&xtb[o * 64 + ci0 + kg * 8];
            if (!ok) a = (short8)(0);
            af[m] = a;
        }
        short8 bf[2];
#pragma unroll
        for (int nn = 0; nn < 2; ++nn)
            bf[nn] = *(const short8*)&woh[((nn * 16 + l15) * 9 + tap) * 64 + ci0 + kg * 8];
#pragma unroll
        for (int m = 0; m < 2; ++m)
#pragma unroll
            for (int nn = 0; nn < 2; ++nn)
                acc[m][nn] = __builtin_amdgcn_mfma_f32_16x16x32_bf16(af[m], bf[nn], acc[m][nn], 0, 0, 0);
    }

    float s1[2] = {0.f, 0.f}, s2[2] = {0.f, 0.f};
#pragma unroll
    for (int m = 0; m < 2; ++m)
#pragma unroll
        for (int nn = 0; nn < 2; ++nn) {
            int co = nn * 16 + l15;
            f32x4 v = acc[m][nn];
            s1[nn] += v.x + v.y + v.z + v.w;
            s2[nn] += v.x * v.x + v.y * v.y + v.z * v.z + v.w * v.w;
            if (co < 18) {
                int br = co < 9 ? 0 : 1;
                int k = co - br * 9;
                int plane = (br * 8 + b) * 9 + k;
                int px = px0 + m * 16 + kg * 4;
                *(f32x4*)&off_raw[(size_t)plane * HW + px] = v;
            }
        }
#pragma unroll
    for (int off = 16; off <= 32; off <<= 1)
#pragma unroll
        for (int nn = 0; nn < 2; ++nn) {
            s1[nn] += __shfl_xor(s1[nn], off);
            s2[nn] += __shfl_xor(s2[nn], off);
        }
    if (l < 16) {
        int idx = ((l15 * 8 + b) * 512 + tile) * 2;
        bnp[idx] = s1[0]; bnp[idx + 1] = s2[0];
        if (l15 < 2) {
            int idx2 = (((16 + l15) * 8 + b) * 512 + tile) * 2;
            bnp[idx2] = s1[1]; bnp[idx2 + 1] = s2[1];
        }
    }
}

__device__ inline void block_reduce2(float& s1, float& s2) {
    __shared__ float sh[4][2];
#pragma unroll
    for (int o = 32; o > 0; o >>= 1) {
        s1 += __shfl_down(s1, o);
        s2 += __shfl_down(s2, o);
    }
    int wid = threadIdx.x >> 6, lane = threadIdx.x & 63;
    if (lane == 0) { sh[wid][0] = s1; sh[wid][1] = s2; }
    __syncthreads();
    if (threadIdx.x == 0)
        for (int i = 1; i < 4; ++i) { s1 += sh[i][0]; s2 += sh[i][1]; }
}

__global__ __launch_bounds__(256) void bn_fin2(const float* __restrict__ bnp,
                                               float* __restrict__ bn_stat) {
    int c = blockIdx.x;                // 0..17
    float s1 = 0.f, s2 = 0.f;
    for (int i = threadIdx.x; i < 4096; i += 256) {
        s1 += bnp[(c * 4096 + i) * 2];
        s2 += bnp[(c * 4096 + i) * 2 + 1];
    }
    block_reduce2(s1, s2);
    if (threadIdx.x == 0) {
        const float N = 8.f * 16384.f;
        float m = s1 / N;
        float var = s2 / N - m * m;
        bn_stat[c * 2] = m;
        bn_stat[c * 2 + 1] = rsqrtf(var + 1e-5f);
    }
}

// ---------------- snake conv: raw-A MFMA + f32 accumulator blend ----------------
// 2048 blocks x 256 thr (4 independent waves). b=n&7 (XCD-pinned),
// rest=n>>3: br=rest>>7, tgrp=rest&127, tile=tgrp*4+wid. 32 px x 64 co per wave.
__global__ __launch_bounds__(256, 5) void snake2(const unsigned short* __restrict__ xt,
                                                 const unsigned short* __restrict__ wrh,
                                                 const float* __restrict__ cb0,
                                                 const float* __restrict__ cb1,
                                                 const float* __restrict__ off_raw,
                                                 const float* __restrict__ bn_stat,
                                                 const float* __restrict__ bng0,
                                                 const float* __restrict__ bnb0,
                                                 const float* __restrict__ bng1,
                                                 const float* __restrict__ bnb1,
                                                 float* __restrict__ out,
                                                 float* __restrict__ gnp) {
    int n = blockIdx.x;
    int b = n & 7;
    int rest = n >> 3;
    int br = rest >> 7;
    int tgrp = rest & 127;
    int t = threadIdx.x;
    int wid = t >> 6, l = t & 63;
    int tile = tgrp * 4 + wid;
    int px0 = tile * 32;
    int l15 = l & 15, kg = l >> 4;
    int lp = l & 31;                   // own pixel lane (32-63 duplicate)
    int h = px0 >> 7;
    int wb = px0 & 127;
    const unsigned short* xtb = xt + (size_t)b * HW * 64;
    const float* bng = br ? bng1 : bng0;
    const float* bnb = br ? bnb1 : bnb0;

    // prologue: cumulative tanh offsets for own pixel px0+lp
    int pxo = px0 + lp;
    float tt[9];
#pragma unroll
    for (int k = 0; k < 9; ++k) {
        float raw = off_raw[(size_t)((br * 8 + b) * 9 + k) * HW + pxo];
        float mn = bn_stat[(br * 9 + k) * 2];
        float rs = bn_stat[(br * 9 + k) * 2 + 1];
        int ch = br ? k + 9 : k;
        tt[k] = tanhf((raw - mn) * rs * bng[ch] + bnb[ch]);
    }
    float cum[9];
    cum[4] = 0.f;
    cum[3] = tt[3]; cum[2] = tt[2] + cum[3]; cum[1] = tt[1] + cum[2]; cum[0] = tt[0] + cum[1];
    cum[5] = tt[5]; cum[6] = cum[5] + tt[6]; cum[7] = cum[6] + tt[7]; cum[8] = cum[7] + tt[8];

    f32x4 acc[2][4];
#pragma unroll
    for (int m = 0; m < 2; ++m)
#pragma unroll
        for (int nn = 0; nn < 4; ++nn) acc[m][nn] = (f32x4)(0.f);

    const f32x4 zero = (f32x4)(0.f);

#pragma unroll
    for (int k = 0; k < 9; ++k) {
        // own-pixel sampling descriptor
        int o0, o1; float fw;
        if (br == 0) {
            int col = min(max(wb + lp + k - 4, 0), 127);
            float yc = fminf(fmaxf((float)h + cum[k], 0.f), 127.f);
            int y0 = (int)floorf(yc);
            int y1 = min(y0 + 1, 127);
            fw = yc - (float)y0;
            o0 = y0 * 128 + col;
            o1 = y1 * 128 + col;
        } else {
            int row = min(max(h + k - 4, 0), 127);
            float xcf = fminf(fmaxf((float)(wb + lp) + cum[k], 0.f), 127.f);
            int x0 = (int)floorf(xcf);
            int x1 = min(x0 + 1, 127);
            fw = xcf - (float)x0;
            o0 = row * 128 + x0;
            o1 = row * 128 + x1;
        }
        int opk = o0 | (o1 << 16);
        // redistribute: A-row offsets (rows l15, l15+16) and D-row blend weights
        int opm[2];
        opm[0] = bperm_i(l15, opk);
        opm[1] = bperm_i(l15 + 16, opk);
        f32x4 fv[2];
#pragma unroll
        for (int m = 0; m < 2; ++m) {
            fv[m].x = bperm_f(m * 16 + kg * 4 + 0, fw);
            fv[m].y = bperm_f(m * 16 + kg * 4 + 1, fw);
            fv[m].z = bperm_f(m * 16 + kg * 4 + 2, fw);
            fv[m].w = bperm_f(m * 16 + kg * 4 + 3, fw);
        }
#pragma unroll
        for (int half = 0; half < 2; ++half) {
            int ci0 = half * 32;
            short8 a0[2], a1[2];
#pragma unroll
            for (int m = 0; m < 2; ++m) {
                int om0 = opm[m] & 0xffff;
                int om1 = (opm[m] >> 16) & 0xffff;
                a0[m] = *(const short8*)&xtb[om0 * 64 + ci0 + kg * 8];
                a1[m] = *(const short8*)&xtb[om1 * 64 + ci0 + kg * 8];
            }
            short8 bf[4];
#pragma unroll
            for (int nn = 0; nn < 4; ++nn)
                bf[nn] = *(const short8*)&wrh[(size_t)(((br * 9 + k) * 64 + nn * 16 + l15)) * 64 + ci0 + kg * 8];
#pragma unroll
            for (int m = 0; m < 2; ++m)
#pragma unroll
                for (int nn = 0; nn < 4; ++nn) {
                    f32x4 p0 = __builtin_amdgcn_mfma_f32_16x16x32_bf16(a0[m], bf[nn], zero, 0, 0, 0);
                    f32x4 p1 = __builtin_amdgcn_mfma_f32_16x16x32_bf16(a1[m], bf[nn], zero, 0, 0, 0);
                    f32x4 d = p1 - p0;
                    f32x4 ta = acc[m][nn] + p0;
                    acc[m][nn] = ta + fv[m] * d;
                }
        }
    }

    // epilogue: bias, store, GN partials
    const float* cb = br ? cb1 : cb0;
    float s1[4], s2[4];
#pragma unroll
    for (int nn = 0; nn < 4; ++nn) { s1[nn] = 0.f; s2[nn] = 0.f; }
#pragma unroll
    for (int m = 0; m < 2; ++m) {
#pragma unroll
        for (int nn = 0; nn < 4; ++nn) {
            int co = nn * 16 + l15;
            float bias = cb[co];
            f32x4 v = acc[m][nn];
            f32x4 r;
            r.x = v.x + bias; r.y = v.y + bias; r.z = v.z + bias; r.w = v.w + bias;
            s1[nn] += r.x + r.y + r.z + r.w;
            s2[nn] += r.x * r.x + r.y * r.y + r.z * r.z + r.w * r.w;
            int px = px0 + m * 16 + kg * 4;
            size_t base = ((size_t)(b * 128 + br * 64 + co) << 14) + px;
            *(f32x4*)&out[base] = r;
        }
    }
#pragma unroll
    for (int off = 16; off <= 32; off <<= 1)
#pragma unroll
        for (int nn = 0; nn < 4; ++nn) {
            s1[nn] += __shfl_xor(s1[nn], off);
            s2[nn] += __shfl_xor(s2[nn], off);
        }
#pragma unroll
    for (int off = 1; off <= 2; off <<= 1)
#pragma unroll
        for (int nn = 0; nn < 4; ++nn) {
            s1[nn] += __shfl_xor(s1[nn], off);
            s2[nn] += __shfl_xor(s2[nn], off);
        }
    if ((l & 0x33) == 0) {             // lanes 0,4,8,12
#pragma unroll
        for (int nn = 0; nn < 4; ++nn) {
            int g = nn * 4 + (l >> 2);
            size_t gi = ((size_t)((br * 8 + b) * 512 + tile)) * 32 + g * 2;
            gnp[gi] = s1[nn];
            gnp[gi + 1] = s2[nn];
        }
    }
}

__global__ __launch_bounds__(256) void gn_reduce(const float* __restrict__ gnp,
                                                 float* __restrict__ gn_stat) {
    int sid = blockIdx.x;              // (br*8+b)*16+g
    int bb = sid >> 4;
    int g = sid & 15;
    float s1 = 0.f, s2 = 0.f;
    int t = threadIdx.x;
#pragma unroll
    for (int j = 0; j < 2; ++j) {
        size_t gi = ((size_t)(bb * 512 + t * 2 + j)) * 32 + g * 2;
        s1 += gnp[gi];
        s2 += gnp[gi + 1];
    }
    block_reduce2(s1, s2);
    if (t == 0) {
        const float N = 4.f * 16384.f;
        float m = s1 / N;
        float var = s2 / N - m * m;
        gn_stat[sid * 2] = m;
        gn_stat[sid * 2 + 1] = rsqrtf(var + 1e-5f);
    }
}

__global__ __launch_bounds__(256) void gn_apply(float* __restrict__ out,
                                                const float* __restrict__ gn_stat,
                                                const float* __restrict__ g0,
                                                const float* __restrict__ b0,
                                                const float* __restrict__ g1,
                                                const float* __restrict__ b1) {
    int i = blockIdx.x * 256 + threadIdx.x;
    size_t base = (size_t)i * 4;
    int c = (int)((base >> 14) & 127);
    int b = (int)(base >> 21);
    int br = c >> 6;
    int co = c & 63;
    int sid = (br * 8 + b) * 16 + (co >> 2);
    float m = gn_stat[sid * 2];
    float rs = gn_stat[sid * 2 + 1];
    const float* gg = br ? g1 : g0;
    const float* bb = br ? b1 : b0;
    float ga = gg[co] * rs, be = bb[co] - m * gg[co] * rs;
    f32x4 v = *(f32x4*)&out[base];
    f32x4 r;
    r.x = fmaxf(fmaf(v.x, ga, be), 0.f);
    r.y = fmaxf(fmaf(v.y, ga, be), 0.f);
    r.z = fmaxf(fmaf(v.z, ga, be), 0.f);
    r.w = fmaxf(fmaf(v.w, ga, be), 0.f);
    *(f32x4*)&out[base] = r;
}

extern "C" void kernel_launch(void* const* d_in, const int* in_sizes, int n_in,
                              void* d_out, int out_size, void* d_ws, size_t ws_size,
                              hipStream_t stream) {
    const float* x       = (const float*)d_in[0];
    const float* off_w0  = (const float*)d_in[1];
    const float* bn_g0   = (const float*)d_in[3];
    const float* bn_b0   = (const float*)d_in[4];
    const float* conv_w0 = (const float*)d_in[5];
    const float* conv_b0 = (const float*)d_in[6];
    const float* gn_g0   = (const float*)d_in[7];
    const float* gn_b0   = (const float*)d_in[8];
    const float* off_w1  = (const float*)d_in[9];
    const float* bn_g1   = (const float*)d_in[11];
    const float* bn_b1   = (const float*)d_in[12];
    const float* conv_w1 = (const float*)d_in[13];
    const float* conv_b1 = (const float*)d_in[14];
    const float* gn_g1   = (const float*)d_in[15];
    const float* gn_b1   = (const float*)d_in[16];

    char* ws = (char*)d_ws;
    unsigned short* xt  = (unsigned short*)(ws + XT_OFF);
    unsigned short* wrh = (unsigned short*)(ws + WRH_OFF);
    unsigned short* woh = (unsigned short*)(ws + WOH_OFF);
    float* off_raw = (float*)(ws + RAW_OFF);
    float* bn_stat = (float*)(ws + BNS_OFF);
    float* gnp     = (float*)(ws + GNP_OFF);   // also bnp2 (early phase, stream-ordered)
    float* gn_stat = (float*)(ws + GNS_OFF);
    float* out = (float*)d_out;

    cvt_x<<<512, 256, 0, stream>>>(x, xt);
    repack_w<<<288, 256, 0, stream>>>(conv_w0, conv_w1, wrh);
    repack_wo<<<72, 256, 0, stream>>>(off_w0, off_w1, woh);
    off_mfma<<<1024, 256, 0, stream>>>(xt, woh, off_raw, gnp);
    bn_fin2<<<18, 256, 0, stream>>>(gnp, bn_stat);
    snake2<<<2048, 256, 0, stream>>>(xt, wrh, conv_b0, conv_b1, off_raw, bn_stat,
                                     bn_g0, bn_b0, bn_g1, bn_b1, out, gnp);
    gn_reduce<<<256, 256, 0, stream>>>(gnp, gn_stat);
    gn_apply<<<16384, 256, 0, stream>>>(out, gn_stat, gn_g0, gn_b0, gn_g1, gn_b1);
}

// Round 5
// 1064.491 us; speedup vs baseline: 1.0775x; 1.0775x over previous
//
#include <hip/hip_runtime.h>
#include <hip/hip_bf16.h>

#define HW 16384
#define NB 8
#define CIN 64

typedef short short8 __attribute__((ext_vector_type(8)));
typedef float f32x4 __attribute__((ext_vector_type(4)));

// ---------------- ws layout (BYTE offsets) ----------------
// xt      : [8][HW][64] bf16      0           16,777,216
// wrh     : [2][9][64co][64ci]    16777216    147,456
// woh     : [32co][9tap][64ci]    16924672    36,864 (slot 73,728)
// off_raw : [16][9][HW] f32       17000448    9,437,184
// bn_stat : [18][2] f32           26437632    144
// gnp     : [16][512][16][2] f32  26439168    1,048,576   (aliased: bnp2 [18][4096][2] early)
// gn_stat : [256][2] f32          27487744    2,048
#define XT_OFF   0
#define WRH_OFF  16777216
#define WOH_OFF  16924672
#define RAW_OFF  17000448
#define BNS_OFF  26437632
#define GNP_OFF  26439168
#define GNS_OFF  27487744

__device__ inline unsigned short f2b(float v) {
    __hip_bfloat16 h = __float2bfloat16(v);
    unsigned short u; __builtin_memcpy(&u, &h, 2);
    return u;
}
__device__ inline float bperm_f(int srclane, float v) {
    int r = __builtin_amdgcn_ds_bpermute(srclane << 2, __builtin_bit_cast(int, v));
    return __builtin_bit_cast(float, r);
}
__device__ inline int bperm_i(int srclane, int v) {
    return __builtin_amdgcn_ds_bpermute(srclane << 2, v);
}

// x [b][ci][px] f32  ->  xt [b][px][ci] bf16
__global__ __launch_bounds__(256) void cvt_x(const float* __restrict__ x,
                                             unsigned short* __restrict__ xt) {
    int blk = blockIdx.x;              // 512 = 8b * 64 tiles(256px)
    int b = blk >> 6;
    int px0 = (blk & 63) * 256;
    int t = threadIdx.x;
    __shared__ unsigned short lds[256][72];
    const float* xb = x + (size_t)b * CIN * HW + px0;
    for (int ci = 0; ci < 64; ++ci)
        lds[t][ci] = f2b(xb[ci * HW + t]);
    __syncthreads();
    int wv = t >> 6, l = t & 63;
    unsigned short* dst = xt + ((size_t)(b * HW + px0)) * 64;
    for (int it = 0; it < 8; ++it) {
        int row = it * 32 + wv * 8 + (l >> 3);
        short8 v = *(const short8*)&lds[row][(l & 7) * 8];
        *(short8*)&dst[row * 64 + (l & 7) * 8] = v;
    }
}

__global__ __launch_bounds__(256) void repack_w(const float* __restrict__ w0,
                                                const float* __restrict__ w1,
                                                unsigned short* __restrict__ wrh) {
    int i = blockIdx.x * 256 + threadIdx.x;
    if (i >= 2 * 9 * 64 * 64) return;
    int ci = i & 63;
    int co = (i >> 6) & 63;
    int k  = (i >> 12) % 9;
    int br = i / 36864;
    const float* w = br ? w1 : w0;
    wrh[i] = f2b(w[(co * 64 + ci) * 9 + k]);
}

__global__ __launch_bounds__(256) void repack_wo(const float* __restrict__ w0,
                                                 const float* __restrict__ w1,
                                                 unsigned short* __restrict__ woh) {
    int i = blockIdx.x * 256 + threadIdx.x;
    if (i >= 32 * 9 * 64) return;
    int ci = i & 63;
    int tap = (i >> 6) % 9;
    int co = i / 576;
    float v = 0.f;
    if (co < 9)       v = w0[(co * 64 + ci) * 9 + tap];
    else if (co < 18) v = w1[(co * 64 + ci) * 9 + tap];
    woh[i] = f2b(v);
}

// offset 3x3 conv MFMA + fused BN partials. 1024 blocks x 256 (4 waves, 1 tile each)
__global__ __launch_bounds__(256, 4) void off_mfma(const unsigned short* __restrict__ xt,
                                                   const unsigned short* __restrict__ woh,
                                                   float* __restrict__ off_raw,
                                                   float* __restrict__ bnp) {
    int b = blockIdx.x & 7;
    int tgrp = blockIdx.x >> 3;        // 0..127
    int t = threadIdx.x;
    int wid = t >> 6, l = t & 63;
    int tile = tgrp * 4 + wid;         // 0..511
    int l15 = l & 15, kg = l >> 4;
    int px0 = tile * 32;
    int h = px0 >> 7;
    int w0 = px0 & 127;
    const unsigned short* xtb = xt + (size_t)b * HW * 64;

    f32x4 acc[2][2];
#pragma unroll
    for (int m = 0; m < 2; ++m)
#pragma unroll
        for (int nn = 0; nn < 2; ++nn) acc[m][nn] = (f32x4)(0.f);

#pragma unroll
    for (int s = 0; s < 18; ++s) {
        const int tap = s >> 1, ci0 = (s & 1) * 32;
        const int dy = tap / 3 - 1, dx = tap % 3 - 1;
        int y = h + dy;
        bool yok = (unsigned)y < 128u;
        int yc = min(max(y, 0), 127);
        short8 af[2];
#pragma unroll
        for (int m = 0; m < 2; ++m) {
            int xx = w0 + m * 16 + l15 + dx;
            bool ok = yok && ((unsigned)xx < 128u);
            int xc = min(max(xx, 0), 127);
            int o = yc * 128 + xc;
            short8 a = *(const short8*)&xtb[o * 64 + ci0 + kg * 8];
            if (!ok) a = (short8)(0);
            af[m] = a;
        }
        short8 bf[2];
#pragma unroll
        for (int nn = 0; nn < 2; ++nn)
            bf[nn] = *(const short8*)&woh[((nn * 16 + l15) * 9 + tap) * 64 + ci0 + kg * 8];
#pragma unroll
        for (int m = 0; m < 2; ++m)
#pragma unroll
            for (int nn = 0; nn < 2; ++nn)
                acc[m][nn] = __builtin_amdgcn_mfma_f32_16x16x32_bf16(af[m], bf[nn], acc[m][nn], 0, 0, 0);
    }

    float s1[2] = {0.f, 0.f}, s2[2] = {0.f, 0.f};
#pragma unroll
    for (int m = 0; m < 2; ++m)
#pragma unroll
        for (int nn = 0; nn < 2; ++nn) {
            int co = nn * 16 + l15;
            f32x4 v = acc[m][nn];
            s1[nn] += v.x + v.y + v.z + v.w;
            s2[nn] += v.x * v.x + v.y * v.y + v.z * v.z + v.w * v.w;
            if (co < 18) {
                int br = co < 9 ? 0 : 1;
                int k = co - br * 9;
                int plane = (br * 8 + b) * 9 + k;
                int px = px0 + m * 16 + kg * 4;
                *(f32x4*)&off_raw[(size_t)plane * HW + px] = v;
            }
        }
#pragma unroll
    for (int off = 16; off <= 32; off <<= 1)
#pragma unroll
        for (int nn = 0; nn < 2; ++nn) {
            s1[nn] += __shfl_xor(s1[nn], off);
            s2[nn] += __shfl_xor(s2[nn], off);
        }
    if (l < 16) {
        int idx = ((l15 * 8 + b) * 512 + tile) * 2;
        bnp[idx] = s1[0]; bnp[idx + 1] = s2[0];
        if (l15 < 2) {
            int idx2 = (((16 + l15) * 8 + b) * 512 + tile) * 2;
            bnp[idx2] = s1[1]; bnp[idx2 + 1] = s2[1];
        }
    }
}

__device__ inline void block_reduce2(float& s1, float& s2) {
    __shared__ float sh[4][2];
#pragma unroll
    for (int o = 32; o > 0; o >>= 1) {
        s1 += __shfl_down(s1, o);
        s2 += __shfl_down(s2, o);
    }
    int wid = threadIdx.x >> 6, lane = threadIdx.x & 63;
    if (lane == 0) { sh[wid][0] = s1; sh[wid][1] = s2; }
    __syncthreads();
    if (threadIdx.x == 0)
        for (int i = 1; i < 4; ++i) { s1 += sh[i][0]; s2 += sh[i][1]; }
}

__global__ __launch_bounds__(256) void bn_fin2(const float* __restrict__ bnp,
                                               float* __restrict__ bn_stat) {
    int c = blockIdx.x;                // 0..17
    float s1 = 0.f, s2 = 0.f;
    for (int i = threadIdx.x; i < 4096; i += 256) {
        s1 += bnp[(c * 4096 + i) * 2];
        s2 += bnp[(c * 4096 + i) * 2 + 1];
    }
    block_reduce2(s1, s2);
    if (threadIdx.x == 0) {
        const float N = 8.f * 16384.f;
        float m = s1 / N;
        float var = s2 / N - m * m;
        bn_stat[c * 2] = m;
        bn_stat[c * 2 + 1] = rsqrtf(var + 1e-5f);
    }
}

// ---------------- snake conv: raw-A MFMA + f32 accumulator blend ----------------
// 2048 blocks x 256 thr (4 independent waves). b=n&7 (XCD-pinned),
// rest=n>>3: br=rest>>7, tgrp=rest&127, tile=tgrp*4+wid. 32 px x 64 co per wave.
__global__ __launch_bounds__(256, 3) void snake2(const unsigned short* __restrict__ xt,
                                                 const unsigned short* __restrict__ wrh,
                                                 const float* __restrict__ cb0,
                                                 const float* __restrict__ cb1,
                                                 const float* __restrict__ off_raw,
                                                 const float* __restrict__ bn_stat,
                                                 const float* __restrict__ bng0,
                                                 const float* __restrict__ bnb0,
                                                 const float* __restrict__ bng1,
                                                 const float* __restrict__ bnb1,
                                                 float* __restrict__ out,
                                                 float* __restrict__ gnp) {
    int n = blockIdx.x;
    int b = n & 7;
    int rest = n >> 3;
    int br = rest >> 7;
    int tgrp = rest & 127;
    int t = threadIdx.x;
    int wid = t >> 6, l = t & 63;
    int tile = tgrp * 4 + wid;
    int px0 = tile * 32;
    int l15 = l & 15, kg = l >> 4;
    int lp = l & 31;                   // own pixel lane (32-63 duplicate)
    int h = px0 >> 7;
    int wb = px0 & 127;
    const unsigned short* xtb = xt + (size_t)b * HW * 64;
    const float* bng = br ? bng1 : bng0;
    const float* bnb = br ? bnb1 : bnb0;

    // prologue: cumulative tanh offsets for own pixel px0+lp
    int pxo = px0 + lp;
    float tt[9];
#pragma unroll
    for (int k = 0; k < 9; ++k) {
        float raw = off_raw[(size_t)((br * 8 + b) * 9 + k) * HW + pxo];
        float mn = bn_stat[(br * 9 + k) * 2];
        float rs = bn_stat[(br * 9 + k) * 2 + 1];
        int ch = br ? k + 9 : k;
        tt[k] = tanhf((raw - mn) * rs * bng[ch] + bnb[ch]);
    }
    float cum[9];
    cum[4] = 0.f;
    cum[3] = tt[3]; cum[2] = tt[2] + cum[3]; cum[1] = tt[1] + cum[2]; cum[0] = tt[0] + cum[1];
    cum[5] = tt[5]; cum[6] = cum[5] + tt[6]; cum[7] = cum[6] + tt[7]; cum[8] = cum[7] + tt[8];

    f32x4 acc[2][4];
#pragma unroll
    for (int m = 0; m < 2; ++m)
#pragma unroll
        for (int nn = 0; nn < 4; ++nn) acc[m][nn] = (f32x4)(0.f);

    const f32x4 zero = (f32x4)(0.f);

#pragma unroll
    for (int k = 0; k < 9; ++k) {
        // own-pixel sampling descriptor
        int o0, o1; float fw;
        if (br == 0) {
            int col = min(max(wb + lp + k - 4, 0), 127);
            float yc = fminf(fmaxf((float)h + cum[k], 0.f), 127.f);
            int y0 = (int)floorf(yc);
            int y1 = min(y0 + 1, 127);
            fw = yc - (float)y0;
            o0 = y0 * 128 + col;
            o1 = y1 * 128 + col;
        } else {
            int row = min(max(h + k - 4, 0), 127);
            float xcf = fminf(fmaxf((float)(wb + lp) + cum[k], 0.f), 127.f);
            int x0 = (int)floorf(xcf);
            int x1 = min(x0 + 1, 127);
            fw = xcf - (float)x0;
            o0 = row * 128 + x0;
            o1 = row * 128 + x1;
        }
        int opk = o0 | (o1 << 16);
        // redistribute: A-row offsets (rows l15, l15+16) and D-row blend weights
        int opm[2];
        opm[0] = bperm_i(l15, opk);
        opm[1] = bperm_i(l15 + 16, opk);
        f32x4 fv[2];
#pragma unroll
        for (int m = 0; m < 2; ++m) {
            fv[m].x = bperm_f(m * 16 + kg * 4 + 0, fw);
            fv[m].y = bperm_f(m * 16 + kg * 4 + 1, fw);
            fv[m].z = bperm_f(m * 16 + kg * 4 + 2, fw);
            fv[m].w = bperm_f(m * 16 + kg * 4 + 3, fw);
        }
#pragma unroll
        for (int half = 0; half < 2; ++half) {
            int ci0 = half * 32;
            short8 a0[2], a1[2];
#pragma unroll
            for (int m = 0; m < 2; ++m) {
                int om0 = opm[m] & 0xffff;
                int om1 = (opm[m] >> 16) & 0xffff;
                a0[m] = *(const short8*)&xtb[om0 * 64 + ci0 + kg * 8];
                a1[m] = *(const short8*)&xtb[om1 * 64 + ci0 + kg * 8];
            }
            short8 bf[4];
#pragma unroll
            for (int nn = 0; nn < 4; ++nn)
                bf[nn] = *(const short8*)&wrh[(size_t)(((br * 9 + k) * 64 + nn * 16 + l15)) * 64 + ci0 + kg * 8];
#pragma unroll
            for (int m = 0; m < 2; ++m)
#pragma unroll
                for (int nn = 0; nn < 4; ++nn) {
                    f32x4 p0 = __builtin_amdgcn_mfma_f32_16x16x32_bf16(a0[m], bf[nn], zero, 0, 0, 0);
                    f32x4 p1 = __builtin_amdgcn_mfma_f32_16x16x32_bf16(a1[m], bf[nn], zero, 0, 0, 0);
                    f32x4 d = p1 - p0;
                    f32x4 ta = acc[m][nn] + p0;
                    acc[m][nn] = ta + fv[m] * d;
                }
        }
    }

    // epilogue: bias, store, GN partials
    const float* cb = br ? cb1 : cb0;
    float s1[4], s2[4];
#pragma unroll
    for (int nn = 0; nn < 4; ++nn) { s1[nn] = 0.f; s2[nn] = 0.f; }
#pragma unroll
    for (int m = 0; m < 2; ++m) {
#pragma unroll
        for (int nn = 0; nn < 4; ++nn) {
            int co = nn * 16 + l15;
            float bias = cb[co];
            f32x4 v = acc[m][nn];
            f32x4 r;
            r.x = v.x + bias; r.y = v.y + bias; r.z = v.z + bias; r.w = v.w + bias;
            s1[nn] += r.x + r.y + r.z + r.w;
            s2[nn] += r.x * r.x + r.y * r.y + r.z * r.z + r.w * r.w;
            int px = px0 + m * 16 + kg * 4;
            size_t base = ((size_t)(b * 128 + br * 64 + co) << 14) + px;
            *(f32x4*)&out[base] = r;
        }
    }
#pragma unroll
    for (int off = 16; off <= 32; off <<= 1)
#pragma unroll
        for (int nn = 0; nn < 4; ++nn) {
            s1[nn] += __shfl_xor(s1[nn], off);
            s2[nn] += __shfl_xor(s2[nn], off);
        }
#pragma unroll
    for (int off = 1; off <= 2; off <<= 1)
#pragma unroll
        for (int nn = 0; nn < 4; ++nn) {
            s1[nn] += __shfl_xor(s1[nn], off);
            s2[nn] += __shfl_xor(s2[nn], off);
        }
    if ((l & 0x33) == 0) {             // lanes 0,4,8,12
#pragma unroll
        for (int nn = 0; nn < 4; ++nn) {
            int g = nn * 4 + (l >> 2);
            size_t gi = ((size_t)((br * 8 + b) * 512 + tile)) * 32 + g * 2;
            gnp[gi] = s1[nn];
            gnp[gi + 1] = s2[nn];
        }
    }
}

__global__ __launch_bounds__(256) void gn_reduce(const float* __restrict__ gnp,
                                                 float* __restrict__ gn_stat) {
    int sid = blockIdx.x;              // (br*8+b)*16+g
    int bb = sid >> 4;
    int g = sid & 15;
    float s1 = 0.f, s2 = 0.f;
    int t = threadIdx.x;
#pragma unroll
    for (int j = 0; j < 2; ++j) {
        size_t gi = ((size_t)(bb * 512 + t * 2 + j)) * 32 + g * 2;
        s1 += gnp[gi];
        s2 += gnp[gi + 1];
    }
    block_reduce2(s1, s2);
    if (t == 0) {
        const float N = 4.f * 16384.f;
        float m = s1 / N;
        float var = s2 / N - m * m;
        gn_stat[sid * 2] = m;
        gn_stat[sid * 2 + 1] = rsqrtf(var + 1e-5f);
    }
}

__global__ __launch_bounds__(256) void gn_apply(float* __restrict__ out,
                                                const float* __restrict__ gn_stat,
                                                const float* __restrict__ g0,
                                                const float* __restrict__ b0,
                                                const float* __restrict__ g1,
                                                const float* __restrict__ b1) {
    int i = blockIdx.x * 256 + threadIdx.x;
    size_t base = (size_t)i * 4;
    int c = (int)((base >> 14) & 127);
    int b = (int)(base >> 21);
    int br = c >> 6;
    int co = c & 63;
    int sid = (br * 8 + b) * 16 + (co >> 2);
    float m = gn_stat[sid * 2];
    float rs = gn_stat[sid * 2 + 1];
    const float* gg = br ? g1 : g0;
    const float* bb = br ? b1 : b0;
    float ga = gg[co] * rs, be = bb[co] - m * gg[co] * rs;
    f32x4 v = *(f32x4*)&out[base];
    f32x4 r;
    r.x = fmaxf(fmaf(v.x, ga, be), 0.f);
    r.y = fmaxf(fmaf(v.y, ga, be), 0.f);
    r.z = fmaxf(fmaf(v.z, ga, be), 0.f);
    r.w = fmaxf(fmaf(v.w, ga, be), 0.f);
    *(f32x4*)&out[base] = r;
}

extern "C" void kernel_launch(void* const* d_in, const int* in_sizes, int n_in,
                              void* d_out, int out_size, void* d_ws, size_t ws_size,
                              hipStream_t stream) {
    const float* x       = (const float*)d_in[0];
    const float* off_w0  = (const float*)d_in[1];
    const float* bn_g0   = (const float*)d_in[3];
    const float* bn_b0   = (const float*)d_in[4];
    const float* conv_w0 = (const float*)d_in[5];
    const float* conv_b0 = (const float*)d_in[6];
    const float* gn_g0   = (const float*)d_in[7];
    const float* gn_b0   = (const float*)d_in[8];
    const float* off_w1  = (const float*)d_in[9];
    const float* bn_g1   = (const float*)d_in[11];
    const float* bn_b1   = (const float*)d_in[12];
    const float* conv_w1 = (const float*)d_in[13];
    const float* conv_b1 = (const float*)d_in[14];
    const float* gn_g1   = (const float*)d_in[15];
    const float* gn_b1   = (const float*)d_in[16];

    char* ws = (char*)d_ws;
    unsigned short* xt  = (unsigned short*)(ws + XT_OFF);
    unsigned short* wrh = (unsigned short*)(ws + WRH_OFF);
    unsigned short* woh = (unsigned short*)(ws + WOH_OFF);
    float* off_raw = (float*)(ws + RAW_OFF);
    float* bn_stat = (float*)(ws + BNS_OFF);
    float* gnp     = (float*)(ws + GNP_OFF);   // also bnp2 (early phase, stream-ordered)
    float* gn_stat = (float*)(ws + GNS_OFF);
    float* out = (float*)d_out;

    cvt_x<<<512, 256, 0, stream>>>(x, xt);
    repack_w<<<288, 256, 0, stream>>>(conv_w0, conv_w1, wrh);
    repack_wo<<<72, 256, 0, stream>>>(off_w0, off_w1, woh);
    off_mfma<<<1024, 256, 0, stream>>>(xt, woh, off_raw, gnp);
    bn_fin2<<<18, 256, 0, stream>>>(gnp, bn_stat);
    snake2<<<2048, 256, 0, stream>>>(xt, wrh, conv_b0, conv_b1, off_raw, bn_stat,
                                     bn_g0, bn_b0, bn_g1, bn_b1, out, gnp);
    gn_reduce<<<256, 256, 0, stream>>>(gnp, gn_stat);
    gn_apply<<<16384, 256, 0, stream>>>(out, gn_stat, gn_g0, gn_b0, gn_g1, gn_b1);
}

// Round 6
// 213.887 us; speedup vs baseline: 5.3626x; 4.9769x over previous
//
#include <hip/hip_runtime.h>
#include <hip/hip_bf16.h>

#define HW 16384
#define NB 8
#define CIN 64

typedef short short8 __attribute__((ext_vector_type(8)));
typedef float f32x4 __attribute__((ext_vector_type(4)));

// ---------------- ws layout (BYTE offsets) ----------------
#define XT_OFF   0
#define WRH_OFF  16777216
#define WOH_OFF  16924672
#define RAW_OFF  17000448
#define BNS_OFF  26437632
#define GNP_OFF  26439168
#define GNS_OFF  27487744

__device__ inline unsigned short f2b(float v) {
    __hip_bfloat16 h = __float2bfloat16(v);
    unsigned short u; __builtin_memcpy(&u, &h, 2);
    return u;
}
__device__ inline float bperm_f(int srclane, float v) {
    int r = __builtin_amdgcn_ds_bpermute(srclane << 2, __builtin_bit_cast(int, v));
    return __builtin_bit_cast(float, r);
}
__device__ inline int bperm_i(int srclane, int v) {
    return __builtin_amdgcn_ds_bpermute(srclane << 2, v);
}

// x [b][ci][px] f32  ->  xt [b][px][ci] bf16
__global__ __launch_bounds__(256) void cvt_x(const float* __restrict__ x,
                                             unsigned short* __restrict__ xt) {
    int blk = blockIdx.x;              // 512 = 8b * 64 tiles(256px)
    int b = blk >> 6;
    int px0 = (blk & 63) * 256;
    int t = threadIdx.x;
    __shared__ unsigned short lds[256][72];
    const float* xb = x + (size_t)b * CIN * HW + px0;
    for (int ci = 0; ci < 64; ++ci)
        lds[t][ci] = f2b(xb[ci * HW + t]);
    __syncthreads();
    int wv = t >> 6, l = t & 63;
    unsigned short* dst = xt + ((size_t)(b * HW + px0)) * 64;
    for (int it = 0; it < 8; ++it) {
        int row = it * 32 + wv * 8 + (l >> 3);
        short8 v = *(const short8*)&lds[row][(l & 7) * 8];
        *(short8*)&dst[row * 64 + (l & 7) * 8] = v;
    }
}

__global__ __launch_bounds__(256) void repack_w(const float* __restrict__ w0,
                                                const float* __restrict__ w1,
                                                unsigned short* __restrict__ wrh) {
    int i = blockIdx.x * 256 + threadIdx.x;
    if (i >= 2 * 9 * 64 * 64) return;
    int ci = i & 63;
    int co = (i >> 6) & 63;
    int k  = (i >> 12) % 9;
    int br = i / 36864;
    const float* w = br ? w1 : w0;
    wrh[i] = f2b(w[(co * 64 + ci) * 9 + k]);
}

__global__ __launch_bounds__(256) void repack_wo(const float* __restrict__ w0,
                                                 const float* __restrict__ w1,
                                                 unsigned short* __restrict__ woh) {
    int i = blockIdx.x * 256 + threadIdx.x;
    if (i >= 32 * 9 * 64) return;
    int ci = i & 63;
    int tap = (i >> 6) % 9;
    int co = i / 576;
    float v = 0.f;
    if (co < 9)       v = w0[(co * 64 + ci) * 9 + tap];
    else if (co < 18) v = w1[(co * 64 + ci) * 9 + tap];
    woh[i] = f2b(v);
}

// offset 3x3 conv MFMA + fused BN partials. 1024 blocks x 256 (4 waves, 1 tile each)
__global__ __launch_bounds__(256, 4) void off_mfma(const unsigned short* __restrict__ xt,
                                                   const unsigned short* __restrict__ woh,
                                                   float* __restrict__ off_raw,
                                                   float* __restrict__ bnp) {
    int b = blockIdx.x & 7;
    int tgrp = blockIdx.x >> 3;        // 0..127
    int t = threadIdx.x;
    int wid = t >> 6, l = t & 63;
    int tile = tgrp * 4 + wid;         // 0..511
    int l15 = l & 15, kg = l >> 4;
    int px0 = tile * 32;
    int h = px0 >> 7;
    int w0 = px0 & 127;
    const unsigned short* xtb = xt + (size_t)b * HW * 64;

    f32x4 acc[2][2];
#pragma unroll
    for (int m = 0; m < 2; ++m)
#pragma unroll
        for (int nn = 0; nn < 2; ++nn) acc[m][nn] = (f32x4)(0.f);

#pragma unroll
    for (int s = 0; s < 18; ++s) {
        const int tap = s >> 1, ci0 = (s & 1) * 32;
        const int dy = tap / 3 - 1, dx = tap % 3 - 1;
        int y = h + dy;
        bool yok = (unsigned)y < 128u;
        int yc = min(max(y, 0), 127);
        short8 af[2];
#pragma unroll
        for (int m = 0; m < 2; ++m) {
            int xx = w0 + m * 16 + l15 + dx;
            bool ok = yok && ((unsigned)xx < 128u);
            int xc = min(max(xx, 0), 127);
            int o = yc * 128 + xc;
            short8 a = *(const short8*)&xtb[o * 64 + ci0 + kg * 8];
            if (!ok) a = (short8)(0);
            af[m] = a;
        }
        short8 bf[2];
#pragma unroll
        for (int nn = 0; nn < 2; ++nn)
            bf[nn] = *(const short8*)&woh[((nn * 16 + l15) * 9 + tap) * 64 + ci0 + kg * 8];
#pragma unroll
        for (int m = 0; m < 2; ++m)
#pragma unroll
            for (int nn = 0; nn < 2; ++nn)
                acc[m][nn] = __builtin_amdgcn_mfma_f32_16x16x32_bf16(af[m], bf[nn], acc[m][nn], 0, 0, 0);
    }

    float s1[2] = {0.f, 0.f}, s2[2] = {0.f, 0.f};
#pragma unroll
    for (int m = 0; m < 2; ++m)
#pragma unroll
        for (int nn = 0; nn < 2; ++nn) {
            int co = nn * 16 + l15;
            f32x4 v = acc[m][nn];
            s1[nn] += v.x + v.y + v.z + v.w;
            s2[nn] += v.x * v.x + v.y * v.y + v.z * v.z + v.w * v.w;
            if (co < 18) {
                int br = co < 9 ? 0 : 1;
                int k = co - br * 9;
                int plane = (br * 8 + b) * 9 + k;
                int px = px0 + m * 16 + kg * 4;
                *(f32x4*)&off_raw[(size_t)plane * HW + px] = v;
            }
        }
#pragma unroll
    for (int off = 16; off <= 32; off <<= 1)
#pragma unroll
        for (int nn = 0; nn < 2; ++nn) {
            s1[nn] += __shfl_xor(s1[nn], off);
            s2[nn] += __shfl_xor(s2[nn], off);
        }
    if (l < 16) {
        int idx = ((l15 * 8 + b) * 512 + tile) * 2;
        bnp[idx] = s1[0]; bnp[idx + 1] = s2[0];
        if (l15 < 2) {
            int idx2 = (((16 + l15) * 8 + b) * 512 + tile) * 2;
            bnp[idx2] = s1[1]; bnp[idx2 + 1] = s2[1];
        }
    }
}

__device__ inline void block_reduce2(float& s1, float& s2) {
    __shared__ float sh[4][2];
#pragma unroll
    for (int o = 32; o > 0; o >>= 1) {
        s1 += __shfl_down(s1, o);
        s2 += __shfl_down(s2, o);
    }
    int wid = threadIdx.x >> 6, lane = threadIdx.x & 63;
    if (lane == 0) { sh[wid][0] = s1; sh[wid][1] = s2; }
    __syncthreads();
    if (threadIdx.x == 0)
        for (int i = 1; i < 4; ++i) { s1 += sh[i][0]; s2 += sh[i][1]; }
}

__global__ __launch_bounds__(256) void bn_fin2(const float* __restrict__ bnp,
                                               float* __restrict__ bn_stat) {
    int c = blockIdx.x;                // 0..17
    float s1 = 0.f, s2 = 0.f;
    for (int i = threadIdx.x; i < 4096; i += 256) {
        s1 += bnp[(c * 4096 + i) * 2];
        s2 += bnp[(c * 4096 + i) * 2 + 1];
    }
    block_reduce2(s1, s2);
    if (threadIdx.x == 0) {
        const float N = 8.f * 16384.f;
        float m = s1 / N;
        float var = s2 / N - m * m;
        bn_stat[c * 2] = m;
        bn_stat[c * 2 + 1] = rsqrtf(var + 1e-5f);
    }
}

// ---------------- snake conv: raw-A MFMA + f32 fma blend ----------------
// 2048 blocks x 256 thr (4 independent waves). b=n&7 (XCD-pinned).
// k-loop NOT unrolled (R4 post-mortem: full unroll demoted acc to scratch).
__global__ __launch_bounds__(256) void snake2(const unsigned short* __restrict__ xt,
                                              const unsigned short* __restrict__ wrh,
                                              const float* __restrict__ cb0,
                                              const float* __restrict__ cb1,
                                              const float* __restrict__ off_raw,
                                              const float* __restrict__ bn_stat,
                                              const float* __restrict__ bng0,
                                              const float* __restrict__ bnb0,
                                              const float* __restrict__ bng1,
                                              const float* __restrict__ bnb1,
                                              float* __restrict__ out,
                                              float* __restrict__ gnp) {
    int n = blockIdx.x;
    int b = n & 7;
    int rest = n >> 3;
    int br = rest >> 7;
    int tgrp = rest & 127;
    int t = threadIdx.x;
    int wid = t >> 6, l = t & 63;
    int tile = tgrp * 4 + wid;
    int px0 = tile * 32;
    int l15 = l & 15, kg = l >> 4;
    int lp = l & 31;                   // own pixel lane (32-63 duplicate)
    int h = px0 >> 7;
    int wb = px0 & 127;
    const unsigned short* xtb = xt + (size_t)b * HW * 64;
    const float* bng = br ? bng1 : bng0;
    const float* bnb = br ? bnb1 : bnb0;

    // prologue: cumulative tanh offsets for own pixel px0+lp
    int pxo = px0 + lp;
    float cum[9];
    {
        float tt[9];
#pragma unroll
        for (int k = 0; k < 9; ++k) {
            float raw = off_raw[(size_t)((br * 8 + b) * 9 + k) * HW + pxo];
            float mn = bn_stat[(br * 9 + k) * 2];
            float rs = bn_stat[(br * 9 + k) * 2 + 1];
            int ch = br ? k + 9 : k;
            tt[k] = tanhf((raw - mn) * rs * bng[ch] + bnb[ch]);
        }
        cum[4] = 0.f;
        cum[3] = tt[3]; cum[2] = tt[2] + cum[3]; cum[1] = tt[1] + cum[2]; cum[0] = tt[0] + cum[1];
        cum[5] = tt[5]; cum[6] = cum[5] + tt[6]; cum[7] = cum[6] + tt[7]; cum[8] = cum[7] + tt[8];
    }

    f32x4 acc00 = (f32x4)(0.f), acc01 = (f32x4)(0.f), acc02 = (f32x4)(0.f), acc03 = (f32x4)(0.f);
    f32x4 acc10 = (f32x4)(0.f), acc11 = (f32x4)(0.f), acc12 = (f32x4)(0.f), acc13 = (f32x4)(0.f);
    const f32x4 zero = (f32x4)(0.f);
    const f32x4 ones = (f32x4)(1.f);

#pragma unroll 1
    for (int k = 0; k < 9; ++k) {
        // own-pixel sampling descriptor
        int o0, o1; float fw;
        if (br == 0) {
            int col = min(max(wb + lp + k - 4, 0), 127);
            float yc = fminf(fmaxf((float)h + cum[k], 0.f), 127.f);
            int y0 = (int)floorf(yc);
            int y1 = min(y0 + 1, 127);
            fw = yc - (float)y0;
            o0 = y0 * 128 + col;
            o1 = y1 * 128 + col;
        } else {
            int row = min(max(h + k - 4, 0), 127);
            float xcf = fminf(fmaxf((float)(wb + lp) + cum[k], 0.f), 127.f);
            int x0 = (int)floorf(xcf);
            int x1 = min(x0 + 1, 127);
            fw = xcf - (float)x0;
            o0 = row * 128 + x0;
            o1 = row * 128 + x1;
        }
        int opk = o0 | (o1 << 16);
        int opm0 = bperm_i(l15, opk);
        int opm1 = bperm_i(l15 + 16, opk);
        f32x4 fv0, fv1;
#pragma unroll
        for (int j = 0; j < 4; ++j) {
            fv0[j] = bperm_f(kg * 4 + j, fw);
            fv1[j] = bperm_f(16 + kg * 4 + j, fw);
        }
        f32x4 om0 = ones - fv0;
        f32x4 om1 = ones - fv1;
        const unsigned short* wk = wrh + (size_t)((br * 9 + k) * 64) * 64;

#pragma unroll
        for (int half = 0; half < 2; ++half) {
            int ci = half * 32 + kg * 8;
            short8 a00 = *(const short8*)&xtb[(opm0 & 0xffff) * 64 + ci];
            short8 a01 = *(const short8*)&xtb[((unsigned)opm0 >> 16) * 64 + ci];
            short8 a10 = *(const short8*)&xtb[(opm1 & 0xffff) * 64 + ci];
            short8 a11 = *(const short8*)&xtb[((unsigned)opm1 >> 16) * 64 + ci];
            short8 bf0 = *(const short8*)&wk[(0 * 16 + l15) * 64 + ci];
            short8 bf1 = *(const short8*)&wk[(1 * 16 + l15) * 64 + ci];
            short8 bf2 = *(const short8*)&wk[(2 * 16 + l15) * 64 + ci];
            short8 bf3 = *(const short8*)&wk[(3 * 16 + l15) * 64 + ci];
#define BLND(ACC, A0, A1, BF, OMF, FVV)                                          \
            {                                                                    \
                f32x4 p0 = __builtin_amdgcn_mfma_f32_16x16x32_bf16(A0, BF, zero, 0, 0, 0); \
                f32x4 p1 = __builtin_amdgcn_mfma_f32_16x16x32_bf16(A1, BF, zero, 0, 0, 0); \
                ACC += OMF * p0;                                                 \
                ACC += FVV * p1;                                                 \
            }
            BLND(acc00, a00, a01, bf0, om0, fv0)
            BLND(acc01, a00, a01, bf1, om0, fv0)
            BLND(acc02, a00, a01, bf2, om0, fv0)
            BLND(acc03, a00, a01, bf3, om0, fv0)
            BLND(acc10, a10, a11, bf0, om1, fv1)
            BLND(acc11, a10, a11, bf1, om1, fv1)
            BLND(acc12, a10, a11, bf2, om1, fv1)
            BLND(acc13, a10, a11, bf3, om1, fv1)
#undef BLND
        }
    }

    // epilogue: bias, store, GN partials (low pressure; static-index array ok)
    f32x4 accA[2][4] = {{acc00, acc01, acc02, acc03}, {acc10, acc11, acc12, acc13}};
    const float* cb = br ? cb1 : cb0;
    float s1[4], s2[4];
#pragma unroll
    for (int nn = 0; nn < 4; ++nn) { s1[nn] = 0.f; s2[nn] = 0.f; }
#pragma unroll
    for (int m = 0; m < 2; ++m) {
#pragma unroll
        for (int nn = 0; nn < 4; ++nn) {
            int co = nn * 16 + l15;
            float bias = cb[co];
            f32x4 v = accA[m][nn];
            f32x4 r;
            r.x = v.x + bias; r.y = v.y + bias; r.z = v.z + bias; r.w = v.w + bias;
            s1[nn] += r.x + r.y + r.z + r.w;
            s2[nn] += r.x * r.x + r.y * r.y + r.z * r.z + r.w * r.w;
            int px = px0 + m * 16 + kg * 4;
            size_t base = ((size_t)(b * 128 + br * 64 + co) << 14) + px;
            *(f32x4*)&out[base] = r;
        }
    }
#pragma unroll
    for (int off = 16; off <= 32; off <<= 1)
#pragma unroll
        for (int nn = 0; nn < 4; ++nn) {
            s1[nn] += __shfl_xor(s1[nn], off);
            s2[nn] += __shfl_xor(s2[nn], off);
        }
#pragma unroll
    for (int off = 1; off <= 2; off <<= 1)
#pragma unroll
        for (int nn = 0; nn < 4; ++nn) {
            s1[nn] += __shfl_xor(s1[nn], off);
            s2[nn] += __shfl_xor(s2[nn], off);
        }
    if ((l & 0x33) == 0) {             // lanes 0,4,8,12
#pragma unroll
        for (int nn = 0; nn < 4; ++nn) {
            int g = nn * 4 + (l >> 2);
            size_t gi = ((size_t)((br * 8 + b) * 512 + tile)) * 32 + g * 2;
            gnp[gi] = s1[nn];
            gnp[gi + 1] = s2[nn];
        }
    }
}

__global__ __launch_bounds__(256) void gn_reduce(const float* __restrict__ gnp,
                                                 float* __restrict__ gn_stat) {
    int sid = blockIdx.x;              // (br*8+b)*16+g
    int bb = sid >> 4;
    int g = sid & 15;
    float s1 = 0.f, s2 = 0.f;
    int t = threadIdx.x;
#pragma unroll
    for (int j = 0; j < 2; ++j) {
        size_t gi = ((size_t)(bb * 512 + t * 2 + j)) * 32 + g * 2;
        s1 += gnp[gi];
        s2 += gnp[gi + 1];
    }
    block_reduce2(s1, s2);
    if (t == 0) {
        const float N = 4.f * 16384.f;
        float m = s1 / N;
        float var = s2 / N - m * m;
        gn_stat[sid * 2] = m;
        gn_stat[sid * 2 + 1] = rsqrtf(var + 1e-5f);
    }
}

__global__ __launch_bounds__(256) void gn_apply(float* __restrict__ out,
                                                const float* __restrict__ gn_stat,
                                                const float* __restrict__ g0,
                                                const float* __restrict__ b0,
                                                const float* __restrict__ g1,
                                                const float* __restrict__ b1) {
    int i = blockIdx.x * 256 + threadIdx.x;
    size_t base = (size_t)i * 4;
    int c = (int)((base >> 14) & 127);
    int b = (int)(base >> 21);
    int br = c >> 6;
    int co = c & 63;
    int sid = (br * 8 + b) * 16 + (co >> 2);
    float m = gn_stat[sid * 2];
    float rs = gn_stat[sid * 2 + 1];
    const float* gg = br ? g1 : g0;
    const float* bb = br ? b1 : b0;
    float ga = gg[co] * rs, be = bb[co] - m * gg[co] * rs;
    f32x4 v = *(f32x4*)&out[base];
    f32x4 r;
    r.x = fmaxf(fmaf(v.x, ga, be), 0.f);
    r.y = fmaxf(fmaf(v.y, ga, be), 0.f);
    r.z = fmaxf(fmaf(v.z, ga, be), 0.f);
    r.w = fmaxf(fmaf(v.w, ga, be), 0.f);
    *(f32x4*)&out[base] = r;
}

extern "C" void kernel_launch(void* const* d_in, const int* in_sizes, int n_in,
                              void* d_out, int out_size, void* d_ws, size_t ws_size,
                              hipStream_t stream) {
    const float* x       = (const float*)d_in[0];
    const float* off_w0  = (const float*)d_in[1];
    const float* bn_g0   = (const float*)d_in[3];
    const float* bn_b0   = (const float*)d_in[4];
    const float* conv_w0 = (const float*)d_in[5];
    const float* conv_b0 = (const float*)d_in[6];
    const float* gn_g0   = (const float*)d_in[7];
    const float* gn_b0   = (const float*)d_in[8];
    const float* off_w1  = (const float*)d_in[9];
    const float* bn_g1   = (const float*)d_in[11];
    const float* bn_b1   = (const float*)d_in[12];
    const float* conv_w1 = (const float*)d_in[13];
    const float* conv_b1 = (const float*)d_in[14];
    const float* gn_g1   = (const float*)d_in[15];
    const float* gn_b1   = (const float*)d_in[16];

    char* ws = (char*)d_ws;
    unsigned short* xt  = (unsigned short*)(ws + XT_OFF);
    unsigned short* wrh = (unsigned short*)(ws + WRH_OFF);
    unsigned short* woh = (unsigned short*)(ws + WOH_OFF);
    float* off_raw = (float*)(ws + RAW_OFF);
    float* bn_stat = (float*)(ws + BNS_OFF);
    float* gnp     = (float*)(ws + GNP_OFF);   // also bnp (early phase, stream-ordered)
    float* gn_stat = (float*)(ws + GNS_OFF);
    float* out = (float*)d_out;

    cvt_x<<<512, 256, 0, stream>>>(x, xt);
    repack_w<<<288, 256, 0, stream>>>(conv_w0, conv_w1, wrh);
    repack_wo<<<72, 256, 0, stream>>>(off_w0, off_w1, woh);
    off_mfma<<<1024, 256, 0, stream>>>(xt, woh, off_raw, gnp);
    bn_fin2<<<18, 256, 0, stream>>>(gnp, bn_stat);
    snake2<<<2048, 256, 0, stream>>>(xt, wrh, conv_b0, conv_b1, off_raw, bn_stat,
                                     bn_g0, bn_b0, bn_g1, bn_b1, out, gnp);
    gn_reduce<<<256, 256, 0, stream>>>(gnp, gn_stat);
    gn_apply<<<16384, 256, 0, stream>>>(out, gn_stat, gn_g0, gn_b0, gn_g1, gn_b1);
}

// Round 7
// 166.773 us; speedup vs baseline: 6.8775x; 1.2825x over previous
//
#include <hip/hip_runtime.h>
#include <hip/hip_bf16.h>

#define HW 16384
#define NB 8
#define CIN 64

// snake tile geometry
#define WIN_R 18
#define WIN_C 26
#define CELLS (WIN_R * WIN_C)     // 468
#define CHUNKS (CELLS * 4)        // 1872 x 16B per ci-half
#define BUFB (CELLS * 64)         // 29952 bytes per ci-half buffer

typedef short short8 __attribute__((ext_vector_type(8)));
typedef float f32x4 __attribute__((ext_vector_type(4)));

// ---------------- ws layout (BYTE offsets) ----------------
// xt2     : [8][2][HW][32] bf16   0           16,777,216
// wrh     : [2][9][64co][64ci]    16777216    147,456
// woh     : [32co][9tap][64ci]    16924672    36,864
// off_raw : [16][9][HW] f32       17000448    9,437,184
// bn_stat : [18][2] f32           26437632    144
// gnp     : [16][512][16][2] f32  26439168    1,048,576 (aliased bnp early)
// gn_stat : [256][2] f32          27487744    2,048
#define XT_OFF   0
#define WRH_OFF  16777216
#define WOH_OFF  16924672
#define RAW_OFF  17000448
#define BNS_OFF  26437632
#define GNP_OFF  26439168
#define GNS_OFF  27487744

__device__ inline unsigned short f2b(float v) {
    __hip_bfloat16 h = __float2bfloat16(v);
    unsigned short u; __builtin_memcpy(&u, &h, 2);
    return u;
}
__device__ inline float bperm_f(int srclane, float v) {
    int r = __builtin_amdgcn_ds_bpermute(srclane << 2, __builtin_bit_cast(int, v));
    return __builtin_bit_cast(float, r);
}
__device__ inline int bperm_i(int srclane, int v) {
    return __builtin_amdgcn_ds_bpermute(srclane << 2, v);
}

// x [b][ci][px] f32  ->  xt2 [b][half][px][32ci] bf16
__global__ __launch_bounds__(256) void cvt_x(const float* __restrict__ x,
                                             unsigned short* __restrict__ xt2) {
    int blk = blockIdx.x;              // 512 = 8b * 64 tiles(256px)
    int b = blk >> 6;
    int px0 = (blk & 63) * 256;
    int t = threadIdx.x;
    __shared__ unsigned short lds[256][72];
    const float* xb = x + (size_t)b * CIN * HW + px0;
    for (int ci = 0; ci < 64; ++ci)
        lds[t][ci] = f2b(xb[ci * HW + t]);
    __syncthreads();
    int wv = t >> 6, l = t & 63;
    int chunk = l & 7;                 // 8 chunks of 8 ci
    int half = chunk >> 2, ci8 = chunk & 3;
    for (int it = 0; it < 8; ++it) {
        int row = it * 32 + wv * 8 + (l >> 3);
        short8 v = *(const short8*)&lds[row][chunk * 8];
        unsigned short* dst = xt2 + ((size_t)(b * 2 + half) * HW + px0 + row) * 32 + ci8 * 8;
        *(short8*)dst = v;
    }
}

__global__ __launch_bounds__(256) void repack_w(const float* __restrict__ w0,
                                                const float* __restrict__ w1,
                                                unsigned short* __restrict__ wrh) {
    int i = blockIdx.x * 256 + threadIdx.x;
    if (i >= 2 * 9 * 64 * 64) return;
    int ci = i & 63;
    int co = (i >> 6) & 63;
    int k  = (i >> 12) % 9;
    int br = i / 36864;
    const float* w = br ? w1 : w0;
    wrh[i] = f2b(w[(co * 64 + ci) * 9 + k]);
}

__global__ __launch_bounds__(256) void repack_wo(const float* __restrict__ w0,
                                                 const float* __restrict__ w1,
                                                 unsigned short* __restrict__ woh) {
    int i = blockIdx.x * 256 + threadIdx.x;
    if (i >= 32 * 9 * 64) return;
    int ci = i & 63;
    int tap = (i >> 6) % 9;
    int co = i / 576;
    float v = 0.f;
    if (co < 9)       v = w0[(co * 64 + ci) * 9 + tap];
    else if (co < 18) v = w1[(co * 64 + ci) * 9 + tap];
    woh[i] = f2b(v);
}

// offset 3x3 conv MFMA + fused BN partials. 1024 blocks x 256
__global__ __launch_bounds__(256, 4) void off_mfma(const unsigned short* __restrict__ xt2,
                                                   const unsigned short* __restrict__ woh,
                                                   float* __restrict__ off_raw,
                                                   float* __restrict__ bnp) {
    int b = blockIdx.x & 7;
    int tgrp = blockIdx.x >> 3;
    int t = threadIdx.x;
    int wid = t >> 6, l = t & 63;
    int tile = tgrp * 4 + wid;
    int l15 = l & 15, kg = l >> 4;
    int px0 = tile * 32;
    int h = px0 >> 7;
    int w0 = px0 & 127;

    f32x4 acc[2][2];
#pragma unroll
    for (int m = 0; m < 2; ++m)
#pragma unroll
        for (int nn = 0; nn < 2; ++nn) acc[m][nn] = (f32x4)(0.f);

#pragma unroll
    for (int s = 0; s < 18; ++s) {
        const int tap = s >> 1, half = s & 1;
        const int dy = tap / 3 - 1, dx = tap % 3 - 1;
        const unsigned short* plane = xt2 + (size_t)(b * 2 + half) * HW * 32;
        int y = h + dy;
        bool yok = (unsigned)y < 128u;
        int yc = min(max(y, 0), 127);
        short8 af[2];
#pragma unroll
        for (int m = 0; m < 2; ++m) {
            int xx = w0 + m * 16 + l15 + dx;
            bool ok = yok && ((unsigned)xx < 128u);
            int xc = min(max(xx, 0), 127);
            int o = yc * 128 + xc;
            short8 a = *(const short8*)&plane[(size_t)o * 32 + kg * 8];
            if (!ok) a = (short8)(0);
            af[m] = a;
        }
        short8 bf[2];
#pragma unroll
        for (int nn = 0; nn < 2; ++nn)
            bf[nn] = *(const short8*)&woh[((nn * 16 + l15) * 9 + tap) * 64 + half * 32 + kg * 8];
#pragma unroll
        for (int m = 0; m < 2; ++m)
#pragma unroll
            for (int nn = 0; nn < 2; ++nn)
                acc[m][nn] = __builtin_amdgcn_mfma_f32_16x16x32_bf16(af[m], bf[nn], acc[m][nn], 0, 0, 0);
    }

    float s1[2] = {0.f, 0.f}, s2[2] = {0.f, 0.f};
#pragma unroll
    for (int m = 0; m < 2; ++m)
#pragma unroll
        for (int nn = 0; nn < 2; ++nn) {
            int co = nn * 16 + l15;
            f32x4 v = acc[m][nn];
            s1[nn] += v.x + v.y + v.z + v.w;
            s2[nn] += v.x * v.x + v.y * v.y + v.z * v.z + v.w * v.w;
            if (co < 18) {
                int br = co < 9 ? 0 : 1;
                int k = co - br * 9;
                int plane = (br * 8 + b) * 9 + k;
                int px = px0 + m * 16 + kg * 4;
                *(f32x4*)&off_raw[(size_t)plane * HW + px] = v;
            }
        }
#pragma unroll
    for (int off = 16; off <= 32; off <<= 1)
#pragma unroll
        for (int nn = 0; nn < 2; ++nn) {
            s1[nn] += __shfl_xor(s1[nn], off);
            s2[nn] += __shfl_xor(s2[nn], off);
        }
    if (l < 16) {
        int idx = ((l15 * 8 + b) * 512 + tile) * 2;
        bnp[idx] = s1[0]; bnp[idx + 1] = s2[0];
        if (l15 < 2) {
            int idx2 = (((16 + l15) * 8 + b) * 512 + tile) * 2;
            bnp[idx2] = s1[1]; bnp[idx2 + 1] = s2[1];
        }
    }
}

__device__ inline void block_reduce2(float& s1, float& s2) {
    __shared__ float sh[4][2];
#pragma unroll
    for (int o = 32; o > 0; o >>= 1) {
        s1 += __shfl_down(s1, o);
        s2 += __shfl_down(s2, o);
    }
    int wid = threadIdx.x >> 6, lane = threadIdx.x & 63;
    if (lane == 0) { sh[wid][0] = s1; sh[wid][1] = s2; }
    __syncthreads();
    if (threadIdx.x == 0)
        for (int i = 1; i < 4; ++i) { s1 += sh[i][0]; s2 += sh[i][1]; }
}

__global__ __launch_bounds__(256) void bn_fin2(const float* __restrict__ bnp,
                                               float* __restrict__ bn_stat) {
    int c = blockIdx.x;
    float s1 = 0.f, s2 = 0.f;
    for (int i = threadIdx.x; i < 4096; i += 256) {
        s1 += bnp[(c * 4096 + i) * 2];
        s2 += bnp[(c * 4096 + i) * 2 + 1];
    }
    block_reduce2(s1, s2);
    if (threadIdx.x == 0) {
        const float N = 8.f * 16384.f;
        float m = s1 / N;
        float var = s2 / N - m * m;
        bn_stat[c * 2] = m;
        bn_stat[c * 2 + 1] = rsqrtf(var + 1e-5f);
    }
}

// ---------------- snake conv: LDS-windowed gather MFMA ----------------
// 2048 blocks x 256 thr (4 waves). b=n&7 (XCD-pinned), br=(n>>3)>>7,
// tile=(n>>3)&127 -> 8h x 16w pixel tile. Window 18x26 cells x 32ci x 2 halves
// staged to LDS via global_load_lds with pre-swizzled source (rule #21).
__global__ __launch_bounds__(256) void snake3(const unsigned short* __restrict__ xt2,
                                              const unsigned short* __restrict__ wrh,
                                              const float* __restrict__ cb0,
                                              const float* __restrict__ cb1,
                                              const float* __restrict__ off_raw,
                                              const float* __restrict__ bn_stat,
                                              const float* __restrict__ bng0,
                                              const float* __restrict__ bnb0,
                                              const float* __restrict__ bng1,
                                              const float* __restrict__ bnb1,
                                              float* __restrict__ out,
                                              float* __restrict__ gnp) {
    __shared__ __align__(16) unsigned char winbuf[2][BUFB];

    int n = blockIdx.x;
    int b = n & 7;
    int rest = n >> 3;
    int br = rest >> 7;
    int tile = rest & 127;
    int h0 = (tile >> 3) * 8;
    int w0 = (tile & 7) * 16;
    int t = threadIdx.x;
    int wv = t >> 6, l = t & 63;
    int l15 = l & 15, kg = l >> 4;
    int lp = l & 31;                   // own pixel (lanes 32-63 duplicate)

    // ---- stage both ci-half windows (async, swizzled source) ----
#pragma unroll
    for (int half = 0; half < 2; ++half) {
        const unsigned short* plane = xt2 + (size_t)(b * 2 + half) * HW * 32;
#pragma unroll
        for (int it = 0; it < 8; ++it) {
            int d = it * 256 + wv * 64 + l;
            if (d < CHUNKS) {
                int cell = d >> 2;
                int ci8 = (d & 3) ^ (cell & 3);          // inverse swizzle on source
                int s = cell / WIN_C;
                int c = cell - s * WIN_C;
                int row = min(max(h0 - 5 + s, 0), 127);
                int col = min(max(w0 - 5 + c, 0), 127);
                const unsigned short* src = plane + ((size_t)(row * 128 + col)) * 32 + ci8 * 8;
                __builtin_amdgcn_global_load_lds(
                    (const __attribute__((address_space(1))) unsigned int*)src,
                    (__attribute__((address_space(3))) unsigned int*)(&winbuf[half][0] + (it * 256 + wv * 64) * 16),
                    16, 0, 0);
            }
        }
    }

    // ---- prologue: own-pixel cumulative offsets ----
    int hrow = h0 + 2 * wv + (lp >> 4);
    int wcol = w0 + (lp & 15);
    int pxo = hrow * 128 + wcol;
    const float* bng = br ? bng1 : bng0;
    const float* bnb = br ? bnb1 : bnb0;
    float cum[9];
    {
        float tt[9];
#pragma unroll
        for (int k = 0; k < 9; ++k) {
            float raw = off_raw[(size_t)((br * 8 + b) * 9 + k) * HW + pxo];
            float mn = bn_stat[(br * 9 + k) * 2];
            float rs = bn_stat[(br * 9 + k) * 2 + 1];
            int ch = br ? k + 9 : k;
            tt[k] = tanhf((raw - mn) * rs * bng[ch] + bnb[ch]);
        }
        cum[4] = 0.f;
        cum[3] = tt[3]; cum[2] = tt[2] + cum[3]; cum[1] = tt[1] + cum[2]; cum[0] = tt[0] + cum[1];
        cum[5] = tt[5]; cum[6] = cum[5] + tt[6]; cum[7] = cum[6] + tt[7]; cum[8] = cum[7] + tt[8];
    }

    __syncthreads();   // staging complete (compiler drains vmcnt before barrier)

    f32x4 acc00 = (f32x4)(0.f), acc01 = (f32x4)(0.f), acc02 = (f32x4)(0.f), acc03 = (f32x4)(0.f);
    f32x4 acc10 = (f32x4)(0.f), acc11 = (f32x4)(0.f), acc12 = (f32x4)(0.f), acc13 = (f32x4)(0.f);
    const f32x4 zero = (f32x4)(0.f);
    const f32x4 ones = (f32x4)(1.f);

#pragma unroll 1
    for (int k = 0; k < 9; ++k) {
        // own-pixel sampling descriptor -> window cells
        int cell0, cell1; float fw;
        if (br == 0) {
            int col = min(max(wcol + k - 4, 0), 127);
            float yc = fminf(fmaxf((float)hrow + cum[k], 0.f), 127.f);
            int y0 = (int)floorf(yc);
            int y1 = min(y0 + 1, 127);
            fw = yc - (float)y0;
            int cs = col - (w0 - 5);
            cell0 = (y0 - (h0 - 5)) * WIN_C + cs;
            cell1 = (y1 - (h0 - 5)) * WIN_C + cs;
        } else {
            int row = min(max(hrow + k - 4, 0), 127);
            float xcf = fminf(fmaxf((float)wcol + cum[k], 0.f), 127.f);
            int x0 = (int)floorf(xcf);
            int x1 = min(x0 + 1, 127);
            fw = xcf - (float)x0;
            int rs = (row - (h0 - 5)) * WIN_C;
            cell0 = rs + (x0 - (w0 - 5));
            cell1 = rs + (x1 - (w0 - 5));
        }
        int cpk = cell0 | (cell1 << 16);
        int cm0 = bperm_i(l15, cpk);          // A rows m=0 (px l15)
        int cm1 = bperm_i(l15 + 16, cpk);     // A rows m=1 (px l15+16)
        f32x4 fv0, fv1;
#pragma unroll
        for (int j = 0; j < 4; ++j) {
            fv0[j] = bperm_f(kg * 4 + j, fw);
            fv1[j] = bperm_f(16 + kg * 4 + j, fw);
        }
        f32x4 om0 = ones - fv0;
        f32x4 om1 = ones - fv1;
        int c00 = cm0 & 0xffff, c01 = ((unsigned)cm0) >> 16;
        int c10 = cm1 & 0xffff, c11 = ((unsigned)cm1) >> 16;

#pragma unroll
        for (int half = 0; half < 2; ++half) {
            const unsigned char* buf = &winbuf[half][0];
            // swizzled LDS gather reads (matches staged source permutation)
            short8 a00 = *(const short8*)(buf + c00 * 64 + ((kg ^ (c00 & 3)) << 4));
            short8 a01 = *(const short8*)(buf + c01 * 64 + ((kg ^ (c01 & 3)) << 4));
            short8 a10 = *(const short8*)(buf + c10 * 64 + ((kg ^ (c10 & 3)) << 4));
            short8 a11 = *(const short8*)(buf + c11 * 64 + ((kg ^ (c11 & 3)) << 4));
            const unsigned short* wk = wrh + (size_t)((br * 9 + k) * 64) * 64 + half * 32 + kg * 8;
            short8 bf0 = *(const short8*)&wk[(0 * 16 + l15) * 64];
            short8 bf1 = *(const short8*)&wk[(1 * 16 + l15) * 64];
            short8 bf2 = *(const short8*)&wk[(2 * 16 + l15) * 64];
            short8 bf3 = *(const short8*)&wk[(3 * 16 + l15) * 64];
#define BLND(ACC, A0, A1, BF, OMF, FVV)                                          \
            {                                                                    \
                f32x4 p0 = __builtin_amdgcn_mfma_f32_16x16x32_bf16(A0, BF, zero, 0, 0, 0); \
                f32x4 p1 = __builtin_amdgcn_mfma_f32_16x16x32_bf16(A1, BF, zero, 0, 0, 0); \
                ACC += OMF * p0;                                                 \
                ACC += FVV * p1;                                                 \
            }
            BLND(acc00, a00, a01, bf0, om0, fv0)
            BLND(acc01, a00, a01, bf1, om0, fv0)
            BLND(acc02, a00, a01, bf2, om0, fv0)
            BLND(acc03, a00, a01, bf3, om0, fv0)
            BLND(acc10, a10, a11, bf0, om1, fv1)
            BLND(acc11, a10, a11, bf1, om1, fv1)
            BLND(acc12, a10, a11, bf2, om1, fv1)
            BLND(acc13, a10, a11, bf3, om1, fv1)
#undef BLND
        }
    }

    // epilogue: bias, store, GN partials
    f32x4 accA[2][4] = {{acc00, acc01, acc02, acc03}, {acc10, acc11, acc12, acc13}};
    const float* cb = br ? cb1 : cb0;
    float s1[4], s2[4];
#pragma unroll
    for (int nn = 0; nn < 4; ++nn) { s1[nn] = 0.f; s2[nn] = 0.f; }
#pragma unroll
    for (int m = 0; m < 2; ++m) {
        int hm = h0 + 2 * wv + m;
#pragma unroll
        for (int nn = 0; nn < 4; ++nn) {
            int co = nn * 16 + l15;
            float bias = cb[co];
            f32x4 v = accA[m][nn];
            f32x4 r;
            r.x = v.x + bias; r.y = v.y + bias; r.z = v.z + bias; r.w = v.w + bias;
            s1[nn] += r.x + r.y + r.z + r.w;
            s2[nn] += r.x * r.x + r.y * r.y + r.z * r.z + r.w * r.w;
            size_t base = ((size_t)(b * 128 + br * 64 + co) << 14) + hm * 128 + w0 + kg * 4;
            *(f32x4*)&out[base] = r;
        }
    }
#pragma unroll
    for (int off = 16; off <= 32; off <<= 1)
#pragma unroll
        for (int nn = 0; nn < 4; ++nn) {
            s1[nn] += __shfl_xor(s1[nn], off);
            s2[nn] += __shfl_xor(s2[nn], off);
        }
#pragma unroll
    for (int off = 1; off <= 2; off <<= 1)
#pragma unroll
        for (int nn = 0; nn < 4; ++nn) {
            s1[nn] += __shfl_xor(s1[nn], off);
            s2[nn] += __shfl_xor(s2[nn], off);
        }
    if ((l & 0x33) == 0) {             // lanes 0,4,8,12
#pragma unroll
        for (int nn = 0; nn < 4; ++nn) {
            int g = nn * 4 + (l >> 2);
            size_t gi = ((size_t)((br * 8 + b) * 512 + tile * 4 + wv)) * 32 + g * 2;
            gnp[gi] = s1[nn];
            gnp[gi + 1] = s2[nn];
        }
    }
}

__global__ __launch_bounds__(256) void gn_reduce(const float* __restrict__ gnp,
                                                 float* __restrict__ gn_stat) {
    int sid = blockIdx.x;              // (br*8+b)*16+g
    int bb = sid >> 4;
    int g = sid & 15;
    float s1 = 0.f, s2 = 0.f;
    int t = threadIdx.x;
#pragma unroll
    for (int j = 0; j < 2; ++j) {
        size_t gi = ((size_t)(bb * 512 + t * 2 + j)) * 32 + g * 2;
        s1 += gnp[gi];
        s2 += gnp[gi + 1];
    }
    block_reduce2(s1, s2);
    if (t == 0) {
        const float N = 4.f * 16384.f;
        float m = s1 / N;
        float var = s2 / N - m * m;
        gn_stat[sid * 2] = m;
        gn_stat[sid * 2 + 1] = rsqrtf(var + 1e-5f);
    }
}

__global__ __launch_bounds__(256) void gn_apply(float* __restrict__ out,
                                                const float* __restrict__ gn_stat,
                                                const float* __restrict__ g0,
                                                const float* __restrict__ b0,
                                                const float* __restrict__ g1,
                                                const float* __restrict__ b1) {
    int i = blockIdx.x * 256 + threadIdx.x;
    size_t base = (size_t)i * 4;
    int c = (int)((base >> 14) & 127);
    int b = (int)(base >> 21);
    int br = c >> 6;
    int co = c & 63;
    int sid = (br * 8 + b) * 16 + (co >> 2);
    float m = gn_stat[sid * 2];
    float rs = gn_stat[sid * 2 + 1];
    const float* gg = br ? g1 : g0;
    const float* bb = br ? b1 : b0;
    float ga = gg[co] * rs, be = bb[co] - m * gg[co] * rs;
    f32x4 v = *(f32x4*)&out[base];
    f32x4 r;
    r.x = fmaxf(fmaf(v.x, ga, be), 0.f);
    r.y = fmaxf(fmaf(v.y, ga, be), 0.f);
    r.z = fmaxf(fmaf(v.z, ga, be), 0.f);
    r.w = fmaxf(fmaf(v.w, ga, be), 0.f);
    *(f32x4*)&out[base] = r;
}

extern "C" void kernel_launch(void* const* d_in, const int* in_sizes, int n_in,
                              void* d_out, int out_size, void* d_ws, size_t ws_size,
                              hipStream_t stream) {
    const float* x       = (const float*)d_in[0];
    const float* off_w0  = (const float*)d_in[1];
    const float* bn_g0   = (const float*)d_in[3];
    const float* bn_b0   = (const float*)d_in[4];
    const float* conv_w0 = (const float*)d_in[5];
    const float* conv_b0 = (const float*)d_in[6];
    const float* gn_g0   = (const float*)d_in[7];
    const float* gn_b0   = (const float*)d_in[8];
    const float* off_w1  = (const float*)d_in[9];
    const float* bn_g1   = (const float*)d_in[11];
    const float* bn_b1   = (const float*)d_in[12];
    const float* conv_w1 = (const float*)d_in[13];
    const float* conv_b1 = (const float*)d_in[14];
    const float* gn_g1   = (const float*)d_in[15];
    const float* gn_b1   = (const float*)d_in[16];

    char* ws = (char*)d_ws;
    unsigned short* xt2 = (unsigned short*)(ws + XT_OFF);
    unsigned short* wrh = (unsigned short*)(ws + WRH_OFF);
    unsigned short* woh = (unsigned short*)(ws + WOH_OFF);
    float* off_raw = (float*)(ws + RAW_OFF);
    float* bn_stat = (float*)(ws + BNS_OFF);
    float* gnp     = (float*)(ws + GNP_OFF);   // also bnp (early phase, stream-ordered)
    float* gn_stat = (float*)(ws + GNS_OFF);
    float* out = (float*)d_out;

    cvt_x<<<512, 256, 0, stream>>>(x, xt2);
    repack_w<<<288, 256, 0, stream>>>(conv_w0, conv_w1, wrh);
    repack_wo<<<72, 256, 0, stream>>>(off_w0, off_w1, woh);
    off_mfma<<<1024, 256, 0, stream>>>(xt2, woh, off_raw, gnp);
    bn_fin2<<<18, 256, 0, stream>>>(gnp, bn_stat);
    snake3<<<2048, 256, 0, stream>>>(xt2, wrh, conv_b0, conv_b1, off_raw, bn_stat,
                                     bn_g0, bn_b0, bn_g1, bn_b1, out, gnp);
    gn_reduce<<<256, 256, 0, stream>>>(gnp, gn_stat);
    gn_apply<<<16384, 256, 0, stream>>>(out, gn_stat, gn_g0, gn_b0, gn_g1, gn_b1);
}